// Round 1
// baseline (2219.941 us; speedup 1.0000x reference)
//
#include <hip/hip_runtime.h>

#define TPB 256

// ---------- index-width adaptive loads ----------
// Reference declares edge_index as int64; harness may deliver int32 (JAX x64-off).
// Detect on device: for int64 (values in [0, 2e5), little-endian) every odd dword
// (high word) is 0. For int32 uniform data, 4096 sampled odd dwords are ~never all 0.
__global__ void k_detect_i64(const unsigned int* __restrict__ ei, int E,
                             int* __restrict__ flag) {
  __shared__ int nz;
  if (threadIdx.x == 0) nz = 0;
  __syncthreads();
  int step = E / 4096;
  if (step < 1) step = 1;
  for (int t = threadIdx.x; t < 4096; t += blockDim.x) {
    long long pos = 1 + 2LL * (long long)t * step;   // odd dword positions
    if (pos < 2LL * (long long)E && ei[pos] != 0u) atomicAdd(&nz, 1);
  }
  __syncthreads();
  if (threadIdx.x == 0) *flag = (nz == 0) ? 1 : 0;
}

__device__ __forceinline__ int load_idx(const void* __restrict__ p, long long pos,
                                        int is64) {
  if (is64) return (int)(((const long long*)p)[pos]);
  return ((const int*)p)[pos];
}

// ---------- degree / norm ----------
__global__ void k_init_deg(float* __restrict__ deg, int n) {
  int i = blockIdx.x * blockDim.x + threadIdx.x;
  if (i < n) deg[i] = 1.0f;  // self-loop
}

__global__ void k_degree(const void* __restrict__ ei, const int* __restrict__ flag,
                         float* __restrict__ deg, int E) {
  int e = blockIdx.x * blockDim.x + threadIdx.x;
  if (e >= E) return;
  int is64 = *flag;
  int d = load_idx(ei, (long long)E + e, is64);  // dst row
  atomicAdd(&deg[d], 1.0f);
}

__global__ void k_rsqrt_inplace(float* __restrict__ deg, int n) {
  int i = blockIdx.x * blockDim.x + threadIdx.x;
  if (i < n) deg[i] = rsqrtf(deg[i]);
}

// ---------- dense transform: m[n, OUT] = h[n, IN] @ W[IN, OUT] ----------
template <int IN, int OUT>
__global__ void k_transform(const float* __restrict__ h, const float* __restrict__ W,
                            float* __restrict__ m, int n) {
  __shared__ float sW[IN * OUT];
  for (int t = threadIdx.x; t < IN * OUT; t += blockDim.x) sW[t] = W[t];
  __syncthreads();
  int i = blockIdx.x * blockDim.x + threadIdx.x;
  if (i >= n) return;
  float xr[IN];
  const float4* hp = reinterpret_cast<const float4*>(h + (size_t)i * IN);
#pragma unroll
  for (int k4 = 0; k4 < IN / 4; ++k4) {
    float4 v = hp[k4];
    xr[k4 * 4 + 0] = v.x; xr[k4 * 4 + 1] = v.y;
    xr[k4 * 4 + 2] = v.z; xr[k4 * 4 + 3] = v.w;
  }
  float acc[OUT];
#pragma unroll
  for (int c = 0; c < OUT; ++c) acc[c] = 0.0f;
#pragma unroll
  for (int k = 0; k < IN; ++k) {
    float xv = xr[k];
#pragma unroll
    for (int c = 0; c < OUT; ++c) acc[c] = fmaf(xv, sW[k * OUT + c], acc[c]);
  }
  float4* mp = reinterpret_cast<float4*>(m + (size_t)i * OUT);
#pragma unroll
  for (int c4 = 0; c4 < OUT / 4; ++c4)
    mp[c4] = make_float4(acc[c4 * 4], acc[c4 * 4 + 1], acc[c4 * 4 + 2], acc[c4 * 4 + 3]);
}

// ---------- agg[i,:] = m[i,:] * dinv[i]^2  (self-loop term; also zero-fills) ----------
__global__ void k_selfloop_init(const float* __restrict__ m, const float* __restrict__ dinv,
                                float* __restrict__ agg, int n8) {
  int gid = blockIdx.x * blockDim.x + threadIdx.x;
  if (gid >= n8) return;
  int i = gid >> 3;
  float di = dinv[i];
  float s = di * di;
  float4 v = reinterpret_cast<const float4*>(m)[gid];
  v.x *= s; v.y *= s; v.z *= s; v.w *= s;
  reinterpret_cast<float4*>(agg)[gid] = v;
}

// ---------- edge scatter: 8 threads/edge, one float4 slice each ----------
__global__ void k_agg(const void* __restrict__ ei, const int* __restrict__ flag,
                      const float* __restrict__ dinv, const float* __restrict__ m,
                      float* __restrict__ agg, int E) {
  int gid = blockIdx.x * blockDim.x + threadIdx.x;
  if (gid >= E * 8) return;
  int is64 = *flag;
  int e = gid >> 3;
  int q = gid & 7;
  int s = load_idx(ei, e, is64);
  int d = load_idx(ei, (long long)E + e, is64);
  float nm = dinv[s] * dinv[d];
  float4 v = *reinterpret_cast<const float4*>(m + (size_t)s * 32 + q * 4);
  float* ap = agg + (size_t)d * 32 + q * 4;
  atomicAdd(ap + 0, v.x * nm);
  atomicAdd(ap + 1, v.y * nm);
  atomicAdd(ap + 2, v.z * nm);
  atomicAdd(ap + 3, v.w * nm);
}

// ---------- epilogue: out = agg + b (, ReLU) ----------
template <bool RELU>
__global__ void k_bias(const float* __restrict__ agg, const float* __restrict__ b,
                       float* __restrict__ outp, int n8) {
  int gid = blockIdx.x * blockDim.x + threadIdx.x;
  if (gid >= n8) return;
  int q = gid & 7;
  float4 a = reinterpret_cast<const float4*>(agg)[gid];
  const float4 bb = *reinterpret_cast<const float4*>(b + q * 4);
  a.x += bb.x; a.y += bb.y; a.z += bb.z; a.w += bb.w;
  if (RELU) {
    a.x = fmaxf(a.x, 0.0f); a.y = fmaxf(a.y, 0.0f);
    a.z = fmaxf(a.z, 0.0f); a.w = fmaxf(a.w, 0.0f);
  }
  reinterpret_cast<float4*>(outp)[gid] = a;
}

extern "C" void kernel_launch(void* const* d_in, const int* in_sizes, int n_in,
                              void* d_out, int out_size, void* d_ws, size_t ws_size,
                              hipStream_t stream) {
  const float* x  = (const float*)d_in[0];
  const void*  ei = d_in[1];
  const float* W1 = (const float*)d_in[2];
  const float* b1 = (const float*)d_in[3];
  const float* W2 = (const float*)d_in[4];
  const float* b2 = (const float*)d_in[5];
  float* out = (float*)d_out;

  const int N = in_sizes[0] / 16;
  const int E = in_sizes[1] / 2;
  const int N8 = N * 8;
  const int E8 = E * 8;

  char* ws = (char*)d_ws;
  int*   flag = (int*)ws;                              // 256 B slot
  float* dinv = (float*)(ws + 256);                    // N floats
  float* bufA = (float*)(ws + 256 + (size_t)N * 4);    // N*32 floats
  float* bufB = bufA + (size_t)N * 32;                 // N*32 floats

  const int gN  = (N + TPB - 1) / TPB;
  const int gE  = (E + TPB - 1) / TPB;
  const int gN8 = (N8 + TPB - 1) / TPB;
  const int gE8 = (E8 + TPB - 1) / TPB;

  // 0. index-width detect
  k_detect_i64<<<1, TPB, 0, stream>>>((const unsigned int*)ei, E, flag);
  // 1. degrees -> dinv
  k_init_deg<<<gN, TPB, 0, stream>>>(dinv, N);
  k_degree<<<gE, TPB, 0, stream>>>(ei, flag, dinv, E);
  k_rsqrt_inplace<<<gN, TPB, 0, stream>>>(dinv, N);
  // 2. layer 1
  k_transform<16, 32><<<gN, TPB, 0, stream>>>(x, W1, bufA, N);          // m1 -> A
  k_selfloop_init<<<gN8, TPB, 0, stream>>>(bufA, dinv, bufB, N8);       // agg1 -> B
  k_agg<<<gE8, TPB, 0, stream>>>(ei, flag, dinv, bufA, bufB, E);
  k_bias<true><<<gN8, TPB, 0, stream>>>(bufB, b1, bufA, N8);            // h -> A
  // 3. layer 2
  k_transform<32, 32><<<gN, TPB, 0, stream>>>(bufA, W2, bufB, N);       // m2 -> B
  k_selfloop_init<<<gN8, TPB, 0, stream>>>(bufB, dinv, bufA, N8);       // agg2 -> A
  k_agg<<<gE8, TPB, 0, stream>>>(ei, flag, dinv, bufB, bufA, E);
  k_bias<false><<<gN8, TPB, 0, stream>>>(bufA, b2, out, N8);            // out
}

// Round 2
// 487.923 us; speedup vs baseline: 4.5498x; 4.5498x over previous
//
#include <hip/hip_runtime.h>

#define TPB 256

// ---------- index-width adaptive loads ----------
__global__ void k_detect_i64(const unsigned int* __restrict__ ei, int E,
                             int* __restrict__ flag) {
  __shared__ int nz;
  if (threadIdx.x == 0) nz = 0;
  __syncthreads();
  int step = E / 4096;
  if (step < 1) step = 1;
  for (int t = threadIdx.x; t < 4096; t += blockDim.x) {
    long long pos = 1 + 2LL * (long long)t * step;   // odd dword positions
    if (pos < 2LL * (long long)E && ei[pos] != 0u) atomicAdd(&nz, 1);
  }
  __syncthreads();
  if (threadIdx.x == 0) *flag = (nz == 0) ? 1 : 0;
}

__device__ __forceinline__ int load_idx(const void* __restrict__ p, long long pos,
                                        int is64) {
  if (is64) return (int)(((const long long*)p)[pos]);
  return ((const int*)p)[pos];
}

// ---------- CSR build ----------
__global__ void k_zero_i(int* __restrict__ p, int n) {
  int i = blockIdx.x * blockDim.x + threadIdx.x;
  if (i < n) p[i] = 0;
}

__global__ void k_hist(const void* __restrict__ ei, const int* __restrict__ flag,
                       int* __restrict__ degi, int E) {
  int e = blockIdx.x * blockDim.x + threadIdx.x;
  if (e >= E) return;
  int is64 = *flag;
  int d = load_idx(ei, (long long)E + e, is64);
  atomicAdd(&degi[d], 1);
}

__global__ void k_dinv(const int* __restrict__ degi, float* __restrict__ dinv, int n) {
  int i = blockIdx.x * blockDim.x + threadIdx.x;
  if (i < n) dinv[i] = rsqrtf((float)(degi[i] + 1));  // +1 self-loop
}

// inclusive block scan; emit per-block sums
__global__ void k_scan1(const int* __restrict__ degi, int* __restrict__ incl,
                        int* __restrict__ bsums, int n) {
  __shared__ int s[TPB];
  int i = blockIdx.x * TPB + threadIdx.x;
  int v = (i < n) ? degi[i] : 0;
  s[threadIdx.x] = v;
  __syncthreads();
#pragma unroll
  for (int off = 1; off < TPB; off <<= 1) {
    int t = (threadIdx.x >= off) ? s[threadIdx.x - off] : 0;
    __syncthreads();
    s[threadIdx.x] += t;
    __syncthreads();
  }
  if (i < n) incl[i] = s[threadIdx.x];
  if (threadIdx.x == TPB - 1) bsums[blockIdx.x] = s[TPB - 1];
}

// single-block exclusive scan of block sums (nb <= 1024)
__global__ void k_scan2(int* __restrict__ bsums, int nb) {
  __shared__ int s[1024];
  int t = threadIdx.x;
  int v = (t < nb) ? bsums[t] : 0;
  s[t] = v;
  __syncthreads();
#pragma unroll
  for (int off = 1; off < 1024; off <<= 1) {
    int u = (t >= off) ? s[t - off] : 0;
    __syncthreads();
    s[t] += u;
    __syncthreads();
  }
  if (t < nb) bsums[t] = s[t] - v;  // exclusive
}

// starts = exclusive scan; cursor = copy of starts (scatter fill pointer)
__global__ void k_finalize(const int* __restrict__ degi, const int* __restrict__ incl,
                           const int* __restrict__ bsums, int* __restrict__ starts,
                           int* __restrict__ cursor, int n) {
  int i = blockIdx.x * TPB + threadIdx.x;
  if (i >= n) return;
  int st = bsums[blockIdx.x] + incl[i] - degi[i];
  starts[i] = st;
  cursor[i] = st;
}

// place edges into CSR slots; precompute per-edge norm weight
__global__ void k_scatter(const void* __restrict__ ei, const int* __restrict__ flag,
                          const float* __restrict__ dinv, int* __restrict__ cursor,
                          int* __restrict__ ssrc, float* __restrict__ sw, int E) {
  int e = blockIdx.x * blockDim.x + threadIdx.x;
  if (e >= E) return;
  int is64 = *flag;
  int s = load_idx(ei, e, is64);
  int d = load_idx(ei, (long long)E + e, is64);
  int pos = atomicAdd(&cursor[d], 1);
  ssrc[pos] = s;
  sw[pos] = dinv[s] * dinv[d];
}

// ---------- dense transform: m[n, OUT] = h[n, IN] @ W[IN, OUT] ----------
template <int IN, int OUT>
__global__ void k_transform(const float* __restrict__ h, const float* __restrict__ W,
                            float* __restrict__ m, int n) {
  __shared__ float sW[IN * OUT];
  for (int t = threadIdx.x; t < IN * OUT; t += blockDim.x) sW[t] = W[t];
  __syncthreads();
  int i = blockIdx.x * blockDim.x + threadIdx.x;
  if (i >= n) return;
  float xr[IN];
  const float4* hp = reinterpret_cast<const float4*>(h + (size_t)i * IN);
#pragma unroll
  for (int k4 = 0; k4 < IN / 4; ++k4) {
    float4 v = hp[k4];
    xr[k4 * 4 + 0] = v.x; xr[k4 * 4 + 1] = v.y;
    xr[k4 * 4 + 2] = v.z; xr[k4 * 4 + 3] = v.w;
  }
  float acc[OUT];
#pragma unroll
  for (int c = 0; c < OUT; ++c) acc[c] = 0.0f;
#pragma unroll
  for (int k = 0; k < IN; ++k) {
    float xv = xr[k];
#pragma unroll
    for (int c = 0; c < OUT; ++c) acc[c] = fmaf(xv, sW[k * OUT + c], acc[c]);
  }
  float4* mp = reinterpret_cast<float4*>(m + (size_t)i * OUT);
#pragma unroll
  for (int c4 = 0; c4 < OUT / 4; ++c4)
    mp[c4] = make_float4(acc[c4 * 4], acc[c4 * 4 + 1], acc[c4 * 4 + 2], acc[c4 * 4 + 3]);
}

// ---------- gather: 8 threads per dst, float4 channel slice each ----------
// acc = m[dst]*dinv[dst]^2 + sum_edges m[src]*w ; out = acc + b (ReLU opt)
template <bool RELU>
__global__ void k_gather(const int* __restrict__ starts, const int* __restrict__ degi,
                         const int* __restrict__ ssrc, const float* __restrict__ sw,
                         const float* __restrict__ dinv, const float* __restrict__ m,
                         const float* __restrict__ b, float* __restrict__ outp, int n) {
  int gid = blockIdx.x * blockDim.x + threadIdx.x;
  int dst = gid >> 3;
  int q = gid & 7;
  if (dst >= n) return;
  int s0 = starts[dst];
  int dg = degi[dst];
  float dd = dinv[dst];
  float4 acc = *reinterpret_cast<const float4*>(m + (size_t)dst * 32 + q * 4);
  float sl = dd * dd;
  acc.x *= sl; acc.y *= sl; acc.z *= sl; acc.w *= sl;
  for (int j = 0; j < dg; ++j) {
    int s = ssrc[s0 + j];
    float w = sw[s0 + j];
    float4 v = *reinterpret_cast<const float4*>(m + (size_t)s * 32 + q * 4);
    acc.x = fmaf(v.x, w, acc.x);
    acc.y = fmaf(v.y, w, acc.y);
    acc.z = fmaf(v.z, w, acc.z);
    acc.w = fmaf(v.w, w, acc.w);
  }
  const float4 bb = *reinterpret_cast<const float4*>(b + q * 4);
  acc.x += bb.x; acc.y += bb.y; acc.z += bb.z; acc.w += bb.w;
  if (RELU) {
    acc.x = fmaxf(acc.x, 0.0f); acc.y = fmaxf(acc.y, 0.0f);
    acc.z = fmaxf(acc.z, 0.0f); acc.w = fmaxf(acc.w, 0.0f);
  }
  *reinterpret_cast<float4*>(outp + (size_t)dst * 32 + q * 4) = acc;
}

extern "C" void kernel_launch(void* const* d_in, const int* in_sizes, int n_in,
                              void* d_out, int out_size, void* d_ws, size_t ws_size,
                              hipStream_t stream) {
  const float* x  = (const float*)d_in[0];
  const void*  ei = d_in[1];
  const float* W1 = (const float*)d_in[2];
  const float* b1 = (const float*)d_in[3];
  const float* W2 = (const float*)d_in[4];
  const float* b2 = (const float*)d_in[5];
  float* out = (float*)d_out;

  const int N = in_sizes[0] / 16;
  const int E = in_sizes[1] / 2;

  // workspace carve-up (256B aligned)
  char* p = (char*)d_ws;
  auto alloc = [&](size_t bytes) {
    char* r = p;
    p += (bytes + 255) & ~(size_t)255;
    return r;
  };
  int*   flag   = (int*)alloc(4);
  float* dinv   = (float*)alloc((size_t)N * 4);
  int*   degi   = (int*)alloc((size_t)N * 4);
  int*   incl   = (int*)alloc((size_t)N * 4);
  int*   starts = (int*)alloc((size_t)N * 4);
  int*   cursor = (int*)alloc((size_t)N * 4);
  int*   bsums  = (int*)alloc(4096);
  int*   ssrc   = (int*)alloc((size_t)E * 4);
  float* sw     = (float*)alloc((size_t)E * 4);
  float* bufA   = (float*)alloc((size_t)N * 32 * 4);
  float* bufB   = (float*)alloc((size_t)N * 32 * 4);

  const int gN  = (N + TPB - 1) / TPB;
  const int gE  = (E + TPB - 1) / TPB;
  const int gN8 = (N * 8 + TPB - 1) / TPB;

  // 0. index-width detect
  k_detect_i64<<<1, TPB, 0, stream>>>((const unsigned int*)ei, E, flag);
  // 1. CSR build (once, reused by both layers)
  k_zero_i<<<gN, TPB, 0, stream>>>(degi, N);
  k_hist<<<gE, TPB, 0, stream>>>(ei, flag, degi, E);
  k_dinv<<<gN, TPB, 0, stream>>>(degi, dinv, N);
  k_scan1<<<gN, TPB, 0, stream>>>(degi, incl, bsums, N);
  k_scan2<<<1, 1024, 0, stream>>>(bsums, gN);
  k_finalize<<<gN, TPB, 0, stream>>>(degi, incl, bsums, starts, cursor, N);
  k_scatter<<<gE, TPB, 0, stream>>>(ei, flag, dinv, cursor, ssrc, sw, E);
  // 2. layer 1
  k_transform<16, 32><<<gN, TPB, 0, stream>>>(x, W1, bufA, N);
  k_gather<true><<<gN8, TPB, 0, stream>>>(starts, degi, ssrc, sw, dinv, bufA, b1, bufB, N);
  // 3. layer 2
  k_transform<32, 32><<<gN, TPB, 0, stream>>>(bufB, W2, bufA, N);
  k_gather<false><<<gN8, TPB, 0, stream>>>(starts, degi, ssrc, sw, dinv, bufA, b2, out, N);
}

// Round 4
// 433.078 us; speedup vs baseline: 5.1260x; 1.1266x over previous
//
#include <hip/hip_runtime.h>

#define TPB 256
#define EPB 2048  // edges per scatter segment (8 per thread)

// ---------- index-width adaptive loads ----------
__global__ void k_detect_i64(const unsigned int* __restrict__ ei, int E,
                             int* __restrict__ flag) {
  __shared__ int nz;
  if (threadIdx.x == 0) nz = 0;
  __syncthreads();
  int step = E / 4096;
  if (step < 1) step = 1;
  for (int t = threadIdx.x; t < 4096; t += blockDim.x) {
    long long pos = 1 + 2LL * (long long)t * step;   // odd dword positions
    if (pos < 2LL * (long long)E && ei[pos] != 0u) atomicAdd(&nz, 1);
  }
  __syncthreads();
  if (threadIdx.x == 0) *flag = (nz == 0) ? 1 : 0;
}

__device__ __forceinline__ int load_idx(const void* __restrict__ p, long long pos,
                                        int is64) {
  if (is64) return (int)(((const long long*)p)[pos]);
  return ((const int*)p)[pos];
}

// ---------- CSR build ----------
__global__ void k_zero_i(int* __restrict__ p, int n) {
  int i = blockIdx.x * blockDim.x + threadIdx.x;
  if (i < n) p[i] = 0;
}

__global__ void k_hist(const void* __restrict__ ei, const int* __restrict__ flag,
                       int* __restrict__ degi, int E) {
  int e = blockIdx.x * blockDim.x + threadIdx.x;
  if (e >= E) return;
  int is64 = *flag;
  int d = load_idx(ei, (long long)E + e, is64);
  atomicAdd(&degi[d], 1);
}

// inclusive block scan; emit per-block sums
__global__ void k_scan1(const int* __restrict__ degi, int* __restrict__ incl,
                        int* __restrict__ bsums, int n) {
  __shared__ int s[TPB];
  int i = blockIdx.x * TPB + threadIdx.x;
  int v = (i < n) ? degi[i] : 0;
  s[threadIdx.x] = v;
  __syncthreads();
#pragma unroll
  for (int off = 1; off < TPB; off <<= 1) {
    int t = (threadIdx.x >= off) ? s[threadIdx.x - off] : 0;
    __syncthreads();
    s[threadIdx.x] += t;
    __syncthreads();
  }
  if (i < n) incl[i] = s[threadIdx.x];
  if (threadIdx.x == TPB - 1) bsums[blockIdx.x] = s[TPB - 1];
}

// single-block exclusive scan of block sums (nb <= 1024)
__global__ void k_scan2(int* __restrict__ bsums, int nb) {
  __shared__ int s[1024];
  int t = threadIdx.x;
  int v = (t < nb) ? bsums[t] : 0;
  s[t] = v;
  __syncthreads();
#pragma unroll
  for (int off = 1; off < 1024; off <<= 1) {
    int u = (t >= off) ? s[t - off] : 0;
    __syncthreads();
    s[t] += u;
    __syncthreads();
  }
  if (t < nb) bsums[t] = s[t] - v;  // exclusive
}

// starts/cursor + dinv + packed meta {start, deg, dinv_bits, 0}
__global__ void k_finalize(const int* __restrict__ degi, const int* __restrict__ incl,
                           const int* __restrict__ bsums, int* __restrict__ cursor,
                           float* __restrict__ dinv, int4* __restrict__ meta, int n) {
  int i = blockIdx.x * TPB + threadIdx.x;
  if (i >= n) return;
  int dg = degi[i];
  int st = bsums[blockIdx.x] + incl[i] - dg;
  float di = rsqrtf((float)(dg + 1));  // +1 self-loop
  cursor[i] = st;
  dinv[i] = di;
  meta[i] = make_int4(st, dg, __float_as_int(di), 0);
}

// place src indices into CSR slots. Blocks are grouped so that dst-chunk g is
// handled only by blocks with blockIdx%8==g (empirically XCD = blockIdx%8):
// each XCD's scattered writes stay inside a ~1.2 MB window resident in its L2.
__global__ void k_scatter(const void* __restrict__ ei, const int* __restrict__ flag,
                          int* __restrict__ cursor, int* __restrict__ ssrc,
                          int E, int Nc) {
  int g = blockIdx.x & 7;        // dst chunk (== XCD, empirically)
  int seg = blockIdx.x >> 3;     // edge segment
  int lo = g * Nc;
  int hi = lo + Nc;
  int is64 = *flag;
  int base = seg * EPB;
#pragma unroll
  for (int j = 0; j < EPB; j += TPB) {
    int e = base + j + threadIdx.x;
    if (e < E) {
      int d = load_idx(ei, (long long)E + e, is64);
      if (d >= lo && d < hi) {
        int s = load_idx(ei, e, is64);
        int pos = atomicAdd(&cursor[d], 1);
        ssrc[pos] = s;
      }
    }
  }
}

// ---------- dense transform + prescale: msc[i,:] = (h[i,:] @ W) * dinv[i] ----------
template <int IN, int OUT>
__global__ void k_transform(const float* __restrict__ h, const float* __restrict__ W,
                            const float* __restrict__ dinv, float* __restrict__ msc,
                            int n) {
  __shared__ float sW[IN * OUT];
  for (int t = threadIdx.x; t < IN * OUT; t += blockDim.x) sW[t] = W[t];
  __syncthreads();
  int i = blockIdx.x * blockDim.x + threadIdx.x;
  if (i >= n) return;
  float xr[IN];
  const float4* hp = reinterpret_cast<const float4*>(h + (size_t)i * IN);
#pragma unroll
  for (int k4 = 0; k4 < IN / 4; ++k4) {
    float4 v = hp[k4];
    xr[k4 * 4 + 0] = v.x; xr[k4 * 4 + 1] = v.y;
    xr[k4 * 4 + 2] = v.z; xr[k4 * 4 + 3] = v.w;
  }
  float acc[OUT];
#pragma unroll
  for (int c = 0; c < OUT; ++c) acc[c] = 0.0f;
#pragma unroll
  for (int k = 0; k < IN; ++k) {
    float xv = xr[k];
#pragma unroll
    for (int c = 0; c < OUT; ++c) acc[c] = fmaf(xv, sW[k * OUT + c], acc[c]);
  }
  float di = dinv[i];
  float4* mp = reinterpret_cast<float4*>(msc + (size_t)i * OUT);
#pragma unroll
  for (int c4 = 0; c4 < OUT / 4; ++c4)
    mp[c4] = make_float4(acc[c4 * 4] * di, acc[c4 * 4 + 1] * di,
                         acc[c4 * 4 + 2] * di, acc[c4 * 4 + 3] * di);
}

// ---------- gather: 4 threads/dst, two float4 halves each, 2-edge unroll ----------
// out = dinv[d] * (msc[d] + sum_edges msc[src]) + b   (optional ReLU)
template <bool RELU>
__global__ void k_gather(const int4* __restrict__ meta, const int* __restrict__ ssrc,
                         const float* __restrict__ msc, const float* __restrict__ b,
                         float* __restrict__ outp, int n) {
  int gid = blockIdx.x * blockDim.x + threadIdx.x;
  int dst = gid >> 2;
  int q = gid & 3;
  if (dst >= n) return;
  int4 md = meta[dst];
  int s0 = md.x;
  int dg = md.y;
  float dd = __int_as_float(md.z);
  size_t o0 = (size_t)q * 4;        // first half offset within row
  size_t o1 = o0 + 16;              // second half offset
  const float* rd = msc + (size_t)dst * 32;
  float4 a0 = *reinterpret_cast<const float4*>(rd + o0);   // self-loop term
  float4 a1 = *reinterpret_cast<const float4*>(rd + o1);
  int j = 0;
  for (; j + 2 <= dg; j += 2) {
    int s1 = ssrc[s0 + j];
    int s2 = ssrc[s0 + j + 1];
    const float* r1 = msc + (size_t)s1 * 32;
    const float* r2 = msc + (size_t)s2 * 32;
    float4 v0 = *reinterpret_cast<const float4*>(r1 + o0);
    float4 v1 = *reinterpret_cast<const float4*>(r1 + o1);
    float4 w0 = *reinterpret_cast<const float4*>(r2 + o0);
    float4 w1 = *reinterpret_cast<const float4*>(r2 + o1);
    a0.x += v0.x + w0.x; a0.y += v0.y + w0.y; a0.z += v0.z + w0.z; a0.w += v0.w + w0.w;
    a1.x += v1.x + w1.x; a1.y += v1.y + w1.y; a1.z += v1.z + w1.z; a1.w += v1.w + w1.w;
  }
  if (j < dg) {
    int s1 = ssrc[s0 + j];
    const float* r1 = msc + (size_t)s1 * 32;
    float4 v0 = *reinterpret_cast<const float4*>(r1 + o0);
    float4 v1 = *reinterpret_cast<const float4*>(r1 + o1);
    a0.x += v0.x; a0.y += v0.y; a0.z += v0.z; a0.w += v0.w;
    a1.x += v1.x; a1.y += v1.y; a1.z += v1.z; a1.w += v1.w;
  }
  float4 b0 = *reinterpret_cast<const float4*>(b + o0);
  float4 b1 = *reinterpret_cast<const float4*>(b + o1);
  a0.x = fmaf(a0.x, dd, b0.x); a0.y = fmaf(a0.y, dd, b0.y);
  a0.z = fmaf(a0.z, dd, b0.z); a0.w = fmaf(a0.w, dd, b0.w);
  a1.x = fmaf(a1.x, dd, b1.x); a1.y = fmaf(a1.y, dd, b1.y);
  a1.z = fmaf(a1.z, dd, b1.z); a1.w = fmaf(a1.w, dd, b1.w);
  if (RELU) {
    a0.x = fmaxf(a0.x, 0.0f); a0.y = fmaxf(a0.y, 0.0f);
    a0.z = fmaxf(a0.z, 0.0f); a0.w = fmaxf(a0.w, 0.0f);
    a1.x = fmaxf(a1.x, 0.0f); a1.y = fmaxf(a1.y, 0.0f);
    a1.z = fmaxf(a1.z, 0.0f); a1.w = fmaxf(a1.w, 0.0f);
  }
  float* wr = outp + (size_t)dst * 32;
  *reinterpret_cast<float4*>(wr + o0) = a0;
  *reinterpret_cast<float4*>(wr + o1) = a1;
}

extern "C" void kernel_launch(void* const* d_in, const int* in_sizes, int n_in,
                              void* d_out, int out_size, void* d_ws, size_t ws_size,
                              hipStream_t stream) {
  const float* x  = (const float*)d_in[0];
  const void*  ei = d_in[1];
  const float* W1 = (const float*)d_in[2];
  const float* b1 = (const float*)d_in[3];
  const float* W2 = (const float*)d_in[4];
  const float* b2 = (const float*)d_in[5];
  float* out = (float*)d_out;

  const int N = in_sizes[0] / 16;
  const int E = in_sizes[1] / 2;
  const int Nc = (N + 7) / 8;   // dst chunk size per XCD group

  // workspace carve-up (256B aligned)
  char* p = (char*)d_ws;
  auto alloc = [&](size_t bytes) {
    char* r = p;
    p += (bytes + 255) & ~(size_t)255;
    return r;
  };
  int*   flag   = (int*)alloc(4);
  float* dinv   = (float*)alloc((size_t)N * 4);
  int*   degi   = (int*)alloc((size_t)N * 4);
  int*   incl   = (int*)alloc((size_t)N * 4);
  int*   cursor = (int*)alloc((size_t)N * 4);
  int4*  meta   = (int4*)alloc((size_t)N * 16);
  int*   bsums  = (int*)alloc(4096);
  int*   ssrc   = (int*)alloc((size_t)E * 4);
  float* bufA   = (float*)alloc((size_t)N * 32 * 4);
  float* bufB   = (float*)alloc((size_t)N * 32 * 4);

  const int gN  = (N + TPB - 1) / TPB;
  const int gE  = (E + TPB - 1) / TPB;
  const int gN4 = (N * 4 + TPB - 1) / TPB;
  const int gSc = ((E + EPB - 1) / EPB) * 8;

  // 0. index-width detect
  k_detect_i64<<<1, TPB, 0, stream>>>((const unsigned int*)ei, E, flag);
  // 1. CSR build (once, reused by both layers)
  k_zero_i<<<gN, TPB, 0, stream>>>(degi, N);
  k_hist<<<gE, TPB, 0, stream>>>(ei, flag, degi, E);
  k_scan1<<<gN, TPB, 0, stream>>>(degi, incl, bsums, N);
  k_scan2<<<1, 1024, 0, stream>>>(bsums, gN);
  k_finalize<<<gN, TPB, 0, stream>>>(degi, incl, bsums, cursor, dinv, meta, N);
  k_scatter<<<gSc, TPB, 0, stream>>>(ei, flag, cursor, ssrc, E, Nc);
  // 2. layer 1
  k_transform<16, 32><<<gN, TPB, 0, stream>>>(x, W1, dinv, bufA, N);
  k_gather<true><<<gN4, TPB, 0, stream>>>(meta, ssrc, bufA, b1, bufB, N);
  // 3. layer 2
  k_transform<32, 32><<<gN, TPB, 0, stream>>>(bufB, W2, dinv, bufA, N);
  k_gather<false><<<gN4, TPB, 0, stream>>>(meta, ssrc, bufA, b2, out, N);
}